// Round 1
// baseline (1699.955 us; speedup 1.0000x reference)
//
#include <hip/hip_runtime.h>
#include <hip/hip_bf16.h>
#include <float.h>
#include <math.h>

#define Bn   16
#define Nn   8192
#define Cn   256
#define Hn   8
#define DHn  32
#define Mn   32      // N_HASHES * N_BUCKETS
#define DFFn 1024

typedef __attribute__((ext_vector_type(8))) short short8;
typedef __attribute__((ext_vector_type(4))) float f32x4;

__device__ __forceinline__ float bf2f(ushort u) {
    union { unsigned int i; float f; } v; v.i = ((unsigned int)u) << 16; return v.f;
}
__device__ __forceinline__ ushort f2bf(float f) {
    union { float f; unsigned int i; } v; v.f = f;
    unsigned int r = (v.i + 0x7fffu + ((v.i >> 16) & 1u)) >> 16;
    return (ushort)r;
}

// ---------------------------------------------------------------------------
// K1: LayerNorm1 + LSH rotations + argmax bucket + LDS-staged pooling
// One block = 128 tokens of one batch; 4 waves, wave-per-token.
// ---------------------------------------------------------------------------
__global__ __launch_bounds__(256) void ln1_pool_kernel(
    const float* __restrict__ x, const float* __restrict__ rot,
    const float* __restrict__ g1, const float* __restrict__ b1,
    ushort* __restrict__ xbf, float* __restrict__ pooled, float* __restrict__ counts)
{
    __shared__ float rotS[Cn * 16];     // 16 KB  rot[f][o], o = h*4+i
    __shared__ float poolS[Mn][Cn];     // 32 KB
    __shared__ float cntS[Mn];
    __shared__ float xrow[4][Cn];       // 4 KB, one row per wave

    const int tid = threadIdx.x;
    for (int i = tid; i < Cn * 16; i += 256) rotS[i] = rot[i];
    for (int i = tid; i < Mn * Cn; i += 256) ((float*)poolS)[i] = 0.f;
    if (tid < Mn) cntS[tid] = 0.f;
    __syncthreads();

    const int b  = blockIdx.x >> 6;          // 64 blocks per batch
    const int n0 = (blockIdx.x & 63) << 7;   // 128 tokens per block
    const int w = tid >> 6, lane = tid & 63;
    const int o = lane & 15;                 // which of 16 rotation outputs
    const int fbase = (lane >> 4) << 6;      // 64-feature chunk for dot

    for (int it = 0; it < 32; ++it) {
        const int n = n0 + w + (it << 2);
        const size_t roff = ((size_t)b * Nn + n) * Cn;
        float4 xv = *(const float4*)&x[roff + lane * 4];
        float s  = xv.x + xv.y + xv.z + xv.w;
        float s2 = xv.x * xv.x + xv.y * xv.y + xv.z * xv.z + xv.w * xv.w;
        #pragma unroll
        for (int msk = 1; msk < 64; msk <<= 1) { s += __shfl_xor(s, msk); s2 += __shfl_xor(s2, msk); }
        float mean = s * (1.f / Cn);
        float var  = s2 * (1.f / Cn) - mean * mean;
        float rr   = rsqrtf(var + 1e-5f);
        float4 gv = *(const float4*)&g1[lane * 4];
        float4 bv = *(const float4*)&b1[lane * 4];
        float xn[4];
        xn[0] = (xv.x - mean) * rr * gv.x + bv.x;
        xn[1] = (xv.y - mean) * rr * gv.y + bv.y;
        xn[2] = (xv.z - mean) * rr * gv.z + bv.z;
        xn[3] = (xv.w - mean) * rr * gv.w + bv.w;
        ushort4 ub; ub.x = f2bf(xn[0]); ub.y = f2bf(xn[1]); ub.z = f2bf(xn[2]); ub.w = f2bf(xn[3]);
        *(ushort4*)&xbf[roff + lane * 4] = ub;
        *(float4*)&xrow[w][lane * 4] = make_float4(xn[0], xn[1], xn[2], xn[3]);
        __syncthreads();   // uniform across the block (all waves run 32 iters)

        // 16 rotation dots: lane computes output o over feature chunk fbase..fbase+63
        float d = 0.f;
        #pragma unroll 8
        for (int f = 0; f < 64; ++f) d += xrow[w][fbase + f] * rotS[(fbase + f) * 16 + o];
        d += __shfl_xor(d, 16); d += __shfl_xor(d, 32);   // now every lane: full dot for its o

        // gather the 4 dots of this lane's hash group (o & 12)
        float d0 = __shfl(d, (lane & 12));
        float d1 = __shfl(d, (lane & 12) | 1);
        float d2 = __shfl(d, (lane & 12) | 2);
        float d3 = __shfl(d, (lane & 12) | 3);
        int bk = 0; float bb = d0;
        if (d1  > bb) { bb = d1;  bk = 1; }
        if (d2  > bb) { bb = d2;  bk = 2; }
        if (d3  > bb) { bb = d3;  bk = 3; }
        if (-d0 > bb) { bb = -d0; bk = 4; }
        if (-d1 > bb) { bb = -d1; bk = 5; }
        if (-d2 > bb) { bb = -d2; bk = 6; }
        if (-d3 > bb) { bb = -d3; bk = 7; }
        if (lane < 16 && (lane & 3) == 0)
            atomicAdd(&cntS[((lane >> 2) << 3) + bk], 1.f);
        int bk0 = __shfl(bk, 0), bk1 = __shfl(bk, 4), bk2 = __shfl(bk, 8), bk3 = __shfl(bk, 12);
        const int f0 = lane * 4;
        #pragma unroll
        for (int e = 0; e < 4; ++e) {
            atomicAdd(&poolS[bk0][f0 + e],      xn[e]);
            atomicAdd(&poolS[8  + bk1][f0 + e], xn[e]);
            atomicAdd(&poolS[16 + bk2][f0 + e], xn[e]);
            atomicAdd(&poolS[24 + bk3][f0 + e], xn[e]);
        }
    }
    __syncthreads();
    for (int i = tid; i < Mn * Cn; i += 256)
        atomicAdd(&pooled[(size_t)b * Mn * Cn + i], ((float*)poolS)[i]);
    if (tid < Mn) atomicAdd(&counts[b * Mn + tid], cntS[tid]);
}

// ---------------------------------------------------------------------------
// K2: pooled -> rp_x -> k,v  (tiny GEMM, fp32). One block per (b, m).
// ---------------------------------------------------------------------------
__global__ __launch_bounds__(256) void kv_kernel(
    const float* __restrict__ pooled, const float* __restrict__ counts,
    const float* __restrict__ kv_w, float* __restrict__ kbuf, float* __restrict__ vbuf)
{
    __shared__ float rp[Cn];
    const int tid = threadIdx.x;
    const int b = blockIdx.x >> 5;
    const int m = blockIdx.x & 31;
    const float cnt = counts[b * Mn + m];
    rp[tid] = pooled[((size_t)b * Mn + m) * Cn + tid] / (cnt + 1e-20f);
    __syncthreads();
    float a0 = 0.f, a1 = 0.f;
    for (int f = 0; f < Cn; ++f) {
        float rv = rp[f];
        a0 += rv * kv_w[f * 512 + tid];
        a1 += rv * kv_w[f * 512 + 256 + tid];
    }
    const int h = tid >> 5, d = tid & 31;
    kbuf[(((size_t)b * Hn + h) * Mn + m) * DHn + d] = a0;
    vbuf[(((size_t)b * Hn + h) * Mn + m) * DHn + d] = a1;
}

// ---------------------------------------------------------------------------
// GEMM: C[M][N] = A[M][K](bf16) x Bt[N][K](bf16)^T, 128x128 tile, BK=32
// EPI 0: store bf16. EPI 1: +bias, exact GELU, store bf16. EPI 2: +bias+resid, store f32.
// ---------------------------------------------------------------------------
template<int EPI>
__global__ __launch_bounds__(256) void gemm_bt(
    const ushort* __restrict__ A, const ushort* __restrict__ Bt,
    const float* __restrict__ bias, const float* __restrict__ resid,
    void* __restrict__ Cp, int Mrows, int Ncols, int K)
{
    __shared__ ushort As[128][40];   // +8 pad, rows stay 16B aligned (80 B stride)
    __shared__ ushort Bs[128][40];
    const int tid  = threadIdx.x;
    const int lane = tid & 63;
    const int w    = tid >> 6;
    const int wm   = (w >> 1) << 6;
    const int wn   = (w & 1) << 6;
    const int lr   = lane & 15;
    const int lq   = lane >> 4;
    const int m0   = blockIdx.y << 7;
    const int n0   = blockIdx.x << 7;
    const int srow = tid >> 2;
    const int sch  = (tid & 3) << 3;

    f32x4 acc[4][4];
    #pragma unroll
    for (int i = 0; i < 4; i++)
        #pragma unroll
        for (int j = 0; j < 4; j++)
            acc[i][j] = (f32x4){0.f, 0.f, 0.f, 0.f};

    for (int k0 = 0; k0 < K; k0 += 32) {
        *(uint4*)&As[srow][sch]      = *(const uint4*)&A[(size_t)(m0 + srow) * K + k0 + sch];
        *(uint4*)&As[srow + 64][sch] = *(const uint4*)&A[(size_t)(m0 + srow + 64) * K + k0 + sch];
        *(uint4*)&Bs[srow][sch]      = *(const uint4*)&Bt[(size_t)(n0 + srow) * K + k0 + sch];
        *(uint4*)&Bs[srow + 64][sch] = *(const uint4*)&Bt[(size_t)(n0 + srow + 64) * K + k0 + sch];
        __syncthreads();
        short8 af[4], bfr[4];
        #pragma unroll
        for (int i = 0; i < 4; i++) af[i]  = *(const short8*)&As[wm + i * 16 + lr][lq * 8];
        #pragma unroll
        for (int j = 0; j < 4; j++) bfr[j] = *(const short8*)&Bs[wn + j * 16 + lr][lq * 8];
        #pragma unroll
        for (int i = 0; i < 4; i++)
            #pragma unroll
            for (int j = 0; j < 4; j++)
                acc[i][j] = __builtin_amdgcn_mfma_f32_16x16x32_bf16(af[i], bfr[j], acc[i][j], 0, 0, 0);
        __syncthreads();
    }

    #pragma unroll
    for (int i = 0; i < 4; i++) {
        #pragma unroll
        for (int j = 0; j < 4; j++) {
            const int col = n0 + wn + j * 16 + lr;
            #pragma unroll
            for (int r = 0; r < 4; r++) {
                const int rw = m0 + wm + i * 16 + lq * 4 + r;   // C/D: col=lane&15, row=quad*4+reg
                float v = acc[i][j][r];
                if (EPI == 1) { v += bias[col]; v = 0.5f * v * (1.f + erff(v * 0.70710678118654752f)); }
                if (EPI == 2) {
                    v += bias[col] + resid[(size_t)rw * Ncols + col];
                    ((float*)Cp)[(size_t)rw * Ncols + col] = v;
                } else {
                    ((ushort*)Cp)[(size_t)rw * Ncols + col] = f2bf(v);
                }
            }
        }
    }
}

// ---------------------------------------------------------------------------
// K4: attention over 32 pooled tokens + residual + LayerNorm2 -> y (bf16)
// One thread per token; k/v for the batch staged in LDS.
// ---------------------------------------------------------------------------
__global__ __launch_bounds__(256) void attn_ln2_kernel(
    const ushort* __restrict__ q, const float* __restrict__ kbuf, const float* __restrict__ vbuf,
    const float* __restrict__ counts, const float* __restrict__ x,
    const float* __restrict__ g2, const float* __restrict__ b2,
    float* __restrict__ x2, ushort* __restrict__ ybf)
{
    __shared__ float kS[Hn * Mn * DHn];   // 32 KB
    __shared__ float vS[Hn * Mn * DHn];   // 32 KB
    __shared__ float mS[Mn];
    const int tid = threadIdx.x;
    const int b = blockIdx.x >> 5;
    const int n = ((blockIdx.x & 31) << 8) + tid;
    for (int i = tid; i < Hn * Mn * DHn; i += 256) {
        kS[i] = kbuf[(size_t)b * Hn * Mn * DHn + i];
        vS[i] = vbuf[(size_t)b * Hn * Mn * DHn + i];
    }
    if (tid < Mn) mS[tid] = counts[b * Mn + tid];
    __syncthreads();

    const size_t row = (size_t)b * Nn + n;
    float sum = 0.f, sum2 = 0.f;
    for (int h = 0; h < Hn; ++h) {
        float qh[32];
        const ushort* qp = q + row * Cn + h * DHn;
        #pragma unroll
        for (int i = 0; i < 4; ++i) {
            short8 qv = *(const short8*)(qp + i * 8);
            #pragma unroll
            for (int j = 0; j < 8; ++j) qh[i * 8 + j] = bf2f((ushort)qv[j]);
        }
        float p[32]; float mx = -FLT_MAX;
        #pragma unroll
        for (int m = 0; m < 32; ++m) {
            float sv;
            if (mS[m] >= 1.f) {
                sv = 0.f;
                const float* kp = &kS[(h * Mn + m) * DHn];
                #pragma unroll
                for (int dq = 0; dq < 8; ++dq) {
                    float4 k4 = *(const float4*)&kp[dq * 4];
                    sv += qh[dq*4+0]*k4.x + qh[dq*4+1]*k4.y + qh[dq*4+2]*k4.z + qh[dq*4+3]*k4.w;
                }
                sv *= 0.17677669529663687f;   // Dh^-0.5
            } else sv = -FLT_MAX;
            p[m] = sv; mx = fmaxf(mx, sv);
        }
        float den = 0.f;
        #pragma unroll
        for (int m = 0; m < 32; ++m) { float e = __expf(p[m] - mx); p[m] = e; den += e; }
        float inv = 1.f / den;
        float o[32];
        #pragma unroll
        for (int dd = 0; dd < 32; ++dd) o[dd] = 0.f;
        #pragma unroll
        for (int m = 0; m < 32; ++m) {
            float pm = p[m];
            const float* vp = &vS[(h * Mn + m) * DHn];
            #pragma unroll
            for (int dq = 0; dq < 8; ++dq) {
                float4 v4 = *(const float4*)&vp[dq * 4];
                o[dq*4+0] += pm*v4.x; o[dq*4+1] += pm*v4.y; o[dq*4+2] += pm*v4.z; o[dq*4+3] += pm*v4.w;
            }
        }
        #pragma unroll
        for (int dq = 0; dq < 8; ++dq) {
            float4 xv = *(const float4*)&x[row * Cn + h * DHn + dq * 4];
            float r0 = xv.x + o[dq*4+0]*inv;
            float r1 = xv.y + o[dq*4+1]*inv;
            float r2 = xv.z + o[dq*4+2]*inv;
            float r3 = xv.w + o[dq*4+3]*inv;
            *(float4*)&x2[row * Cn + h * DHn + dq * 4] = make_float4(r0, r1, r2, r3);
            sum  += r0 + r1 + r2 + r3;
            sum2 += r0*r0 + r1*r1 + r2*r2 + r3*r3;
        }
    }
    float mean = sum * (1.f / Cn);
    float var  = sum2 * (1.f / Cn) - mean * mean;
    float rr   = rsqrtf(var + 1e-5f);
    for (int i = 0; i < Cn / 4; ++i) {
        float4 xv = *(const float4*)&x2[row * Cn + i * 4];
        float4 gv = *(const float4*)&g2[i * 4];
        float4 bv = *(const float4*)&b2[i * 4];
        ushort4 ub;
        ub.x = f2bf((xv.x - mean) * rr * gv.x + bv.x);
        ub.y = f2bf((xv.y - mean) * rr * gv.y + bv.y);
        ub.z = f2bf((xv.z - mean) * rr * gv.z + bv.z);
        ub.w = f2bf((xv.w - mean) * rr * gv.w + bv.w);
        *(ushort4*)&ybf[row * Cn + i * 4] = ub;
    }
}

// ---------------------------------------------------------------------------
// Weight cast + transpose: W[R][Cc] f32 -> Wt[Cc][R] bf16
// ---------------------------------------------------------------------------
__global__ void wcast_kernel(const float* __restrict__ W, ushort* __restrict__ Wt, int R, int Cc)
{
    int idx = blockIdx.x * 256 + threadIdx.x;
    if (idx < R * Cc) {
        int r = idx / Cc, c = idx % Cc;
        Wt[(size_t)c * R + r] = f2bf(W[idx]);
    }
}

extern "C" void kernel_launch(void* const* d_in, const int* in_sizes, int n_in,
                              void* d_out, int out_size, void* d_ws, size_t ws_size,
                              hipStream_t stream)
{
    const float* x    = (const float*)d_in[0];
    const float* rot  = (const float*)d_in[1];
    const float* n1g  = (const float*)d_in[2];
    const float* n1b  = (const float*)d_in[3];
    const float* q_w  = (const float*)d_in[4];
    const float* kv_w = (const float*)d_in[5];
    const float* n2g  = (const float*)d_in[6];
    const float* n2b  = (const float*)d_in[7];
    const float* fc1w = (const float*)d_in[8];
    const float* fc1b = (const float*)d_in[9];
    const float* fc2w = (const float*)d_in[10];
    const float* fc2b = (const float*)d_in[11];

    char* ws = (char*)d_ws;
    // Workspace layout (~451 MB). h (268MB) aliases x_bf16+q_bf16 (dead by K5).
    const size_t XBF_OFF = 0;                  // 67108864  bf16 x_ [131072][256]
    const size_t QBF_OFF = 67108864ull;        // 67108864  bf16 q
    const size_t H_OFF   = 0;                  // 268435456 bf16 h [131072][1024] (aliases above)
    const size_t X2_OFF  = 268435456ull;       // 134217728 f32 x2
    const size_t Y_OFF   = 402653184ull;       // 67108864  bf16 y
    const size_t PL_OFF  = 469762048ull;       // 524288    f32 pooled [16][32][256]
    const size_t CT_OFF  = PL_OFF + 524288;    // 2048      f32 counts
    const size_t KB_OFF  = CT_OFF + 2048;      // 524288    f32 k [16][8][32][32]
    const size_t VB_OFF  = KB_OFF + 524288;    // 524288    f32 v
    const size_t QWT_OFF = VB_OFF + 524288;    // 131072    bf16 q_w^T
    const size_t F1T_OFF = QWT_OFF + 131072;   // 524288    bf16 fc1^T
    const size_t F2T_OFF = F1T_OFF + 524288;   // 524288    bf16 fc2^T

    ushort* xbf    = (ushort*)(ws + XBF_OFF);
    ushort* qbf    = (ushort*)(ws + QBF_OFF);
    ushort* hbf    = (ushort*)(ws + H_OFF);
    float*  x2     = (float*)(ws + X2_OFF);
    ushort* ybf    = (ushort*)(ws + Y_OFF);
    float*  pooled = (float*)(ws + PL_OFF);
    float*  counts = (float*)(ws + CT_OFF);
    float*  kbuf   = (float*)(ws + KB_OFF);
    float*  vbuf   = (float*)(ws + VB_OFF);
    ushort* qwT    = (ushort*)(ws + QWT_OFF);
    ushort* f1T    = (ushort*)(ws + F1T_OFF);
    ushort* f2T    = (ushort*)(ws + F2T_OFF);

    hipMemsetAsync(ws + PL_OFF, 0, 524288 + 2048, stream);
    wcast_kernel<<<dim3(256), 256, 0, stream>>>(q_w, qwT, 256, 256);
    wcast_kernel<<<dim3(1024), 256, 0, stream>>>(fc1w, f1T, 256, 1024);
    wcast_kernel<<<dim3(1024), 256, 0, stream>>>(fc2w, f2T, 1024, 256);

    ln1_pool_kernel<<<dim3(Bn * 64), 256, 0, stream>>>(x, rot, n1g, n1b, xbf, pooled, counts);
    kv_kernel<<<dim3(Bn * Mn), 256, 0, stream>>>(pooled, counts, kv_w, kbuf, vbuf);
    gemm_bt<0><<<dim3(2, 1024), 256, 0, stream>>>(xbf, qwT, nullptr, nullptr, qbf, Bn * Nn, Cn, Cn);
    attn_ln2_kernel<<<dim3(Bn * 32), 256, 0, stream>>>(qbf, kbuf, vbuf, counts, x, n2g, n2b, x2, ybf);
    gemm_bt<1><<<dim3(8, 1024), 256, 0, stream>>>(ybf, f1T, fc1b, nullptr, hbf, Bn * Nn, DFFn, Cn);
    gemm_bt<2><<<dim3(2, 1024), 256, 0, stream>>>(hbf, f2T, fc2b, x2, d_out, Bn * Nn, Cn, DFFn);
}

// Round 2
// 1648.022 us; speedup vs baseline: 1.0315x; 1.0315x over previous
//
#include <hip/hip_runtime.h>
#include <hip/hip_bf16.h>
#include <float.h>
#include <math.h>

#define Bn   16
#define Nn   8192
#define Cn   256
#define Hn   8
#define DHn  32
#define Mn   32      // N_HASHES * N_BUCKETS
#define DFFn 1024

typedef __attribute__((ext_vector_type(8))) short short8;
typedef __attribute__((ext_vector_type(4))) float f32x4;

__device__ __forceinline__ float bf2f(ushort u) {
    union { unsigned int i; float f; } v; v.i = ((unsigned int)u) << 16; return v.f;
}
__device__ __forceinline__ ushort f2bf(float f) {
    union { float f; unsigned int i; } v; v.f = f;
    unsigned int r = (v.i + 0x7fffu + ((v.i >> 16) & 1u)) >> 16;
    return (ushort)r;
}

// ---------------------------------------------------------------------------
// K1: LayerNorm1 + LSH rotations + argmax bucket + LDS-staged pooling
// One block = 128 tokens of one batch; 4 waves, wave-per-token.
// rot weights register-cached per lane; no in-loop barriers; conflict-free
// pooling layout (lane + e*64 => 2-way bank aliasing = free).
// ---------------------------------------------------------------------------
__global__ __launch_bounds__(256, 4) void ln1_pool_kernel(
    const float* __restrict__ x, const float* __restrict__ rot,
    const float* __restrict__ g1, const float* __restrict__ b1,
    ushort* __restrict__ xbf, float* __restrict__ pooled, float* __restrict__ counts)
{
    __shared__ float poolS[Mn][Cn];     // 32 KB
    __shared__ float cntS[Mn];
    __shared__ float xrow[4][Cn];       // 4 KB, one row per wave

    const int tid  = threadIdx.x;
    const int w    = tid >> 6, lane = tid & 63;
    const int o    = lane & 15;                 // rotation output index (h*4+i)
    const int g    = lane >> 4;                 // feature-chunk group
    const int fbase = g << 6;                   // 64-feature chunk for dot

    // Register-cache this lane's 64 rotation weights: rot[f][o], f in chunk.
    float rwv[64];
    #pragma unroll
    for (int f = 0; f < 64; ++f) rwv[f] = rot[(fbase + f) * 16 + o];

    for (int i = tid; i < Mn * Cn; i += 256) ((float*)poolS)[i] = 0.f;
    if (tid < Mn) cntS[tid] = 0.f;
    __syncthreads();

    const int b  = blockIdx.x >> 6;          // 64 blocks per batch
    const int n0 = (blockIdx.x & 63) << 7;   // 128 tokens per block

    const float4 gv = *(const float4*)&g1[lane * 4];
    const float4 bv = *(const float4*)&b1[lane * 4];

    for (int it = 0; it < 32; ++it) {
        const int n = n0 + w + (it << 2);
        const size_t roff = ((size_t)b * Nn + n) * Cn;
        float4 xv = *(const float4*)&x[roff + lane * 4];
        float s  = xv.x + xv.y + xv.z + xv.w;
        float s2 = xv.x * xv.x + xv.y * xv.y + xv.z * xv.z + xv.w * xv.w;
        #pragma unroll
        for (int msk = 1; msk < 64; msk <<= 1) { s += __shfl_xor(s, msk); s2 += __shfl_xor(s2, msk); }
        float mean = s * (1.f / Cn);
        float var  = s2 * (1.f / Cn) - mean * mean;
        float rr   = rsqrtf(var + 1e-5f);
        float xn[4];
        xn[0] = (xv.x - mean) * rr * gv.x + bv.x;
        xn[1] = (xv.y - mean) * rr * gv.y + bv.y;
        xn[2] = (xv.z - mean) * rr * gv.z + bv.z;
        xn[3] = (xv.w - mean) * rr * gv.w + bv.w;
        ushort4 ub; ub.x = f2bf(xn[0]); ub.y = f2bf(xn[1]); ub.z = f2bf(xn[2]); ub.w = f2bf(xn[3]);
        *(ushort4*)&xbf[roff + lane * 4] = ub;
        *(float4*)&xrow[w][lane * 4] = make_float4(xn[0], xn[1], xn[2], xn[3]);
        // wave-private xrow row: no barrier needed (same-wave LDS RAW)

        // 16 rotation dots: lane computes output o over its 64-feature chunk.
        // Group-staggered order breaks the 4-way same-bank aliasing.
        float d = 0.f;
        #pragma unroll
        for (int jj = 0; jj < 16; ++jj) {
            const int j = (jj + g * 4) & 15;
            float4 x4 = *(const float4*)&xrow[w][fbase + j * 4];
            d += x4.x * rwv[j * 4] + x4.y * rwv[j * 4 + 1]
               + x4.z * rwv[j * 4 + 2] + x4.w * rwv[j * 4 + 3];
        }
        d += __shfl_xor(d, 16); d += __shfl_xor(d, 32);   // full dot for output o

        // gather the 4 dots of this lane's hash group (o & 12)
        float d0 = __shfl(d, (lane & 12));
        float d1 = __shfl(d, (lane & 12) | 1);
        float d2 = __shfl(d, (lane & 12) | 2);
        float d3 = __shfl(d, (lane & 12) | 3);
        int bk = 0; float bb = d0;
        if (d1  > bb) { bb = d1;  bk = 1; }
        if (d2  > bb) { bb = d2;  bk = 2; }
        if (d3  > bb) { bb = d3;  bk = 3; }
        if (-d0 > bb) { bb = -d0; bk = 4; }
        if (-d1 > bb) { bb = -d1; bk = 5; }
        if (-d2 > bb) { bb = -d2; bk = 6; }
        if (-d3 > bb) { bb = -d3; bk = 7; }
        if (lane < 16 && (lane & 3) == 0)
            atomicAdd(&cntS[((lane >> 2) << 3) + bk], 1.f);
        const int bk0 = __shfl(bk, 0), bk1 = __shfl(bk, 4), bk2 = __shfl(bk, 8), bk3 = __shfl(bk, 12);
        #pragma unroll
        for (int e = 0; e < 4; ++e) {
            const int f = lane + (e << 6);       // consecutive across lanes: conflict-free
            const float xv1 = xrow[w][f];
            atomicAdd(&poolS[bk0][f],      xv1);
            atomicAdd(&poolS[8  + bk1][f], xv1);
            atomicAdd(&poolS[16 + bk2][f], xv1);
            atomicAdd(&poolS[24 + bk3][f], xv1);
        }
    }
    __syncthreads();
    for (int i = tid; i < Mn * Cn; i += 256)
        atomicAdd(&pooled[(size_t)b * Mn * Cn + i], ((float*)poolS)[i]);
    if (tid < Mn) atomicAdd(&counts[b * Mn + tid], cntS[tid]);
}

// ---------------------------------------------------------------------------
// K2: pooled -> rp_x -> k,v  (tiny GEMM, fp32). One block per (b, m).
// ---------------------------------------------------------------------------
__global__ __launch_bounds__(256) void kv_kernel(
    const float* __restrict__ pooled, const float* __restrict__ counts,
    const float* __restrict__ kv_w, float* __restrict__ kbuf, float* __restrict__ vbuf)
{
    __shared__ float rp[Cn];
    const int tid = threadIdx.x;
    const int b = blockIdx.x >> 5;
    const int m = blockIdx.x & 31;
    const float cnt = counts[b * Mn + m];
    rp[tid] = pooled[((size_t)b * Mn + m) * Cn + tid] / (cnt + 1e-20f);
    __syncthreads();
    float a0 = 0.f, a1 = 0.f;
    for (int f = 0; f < Cn; ++f) {
        float rv = rp[f];
        a0 += rv * kv_w[f * 512 + tid];
        a1 += rv * kv_w[f * 512 + 256 + tid];
    }
    const int h = tid >> 5, d = tid & 31;
    kbuf[(((size_t)b * Hn + h) * Mn + m) * DHn + d] = a0;
    vbuf[(((size_t)b * Hn + h) * Mn + m) * DHn + d] = a1;
}

// ---------------------------------------------------------------------------
// GEMM: C[M][N] = A[M][K](bf16) x Bt[N][K](bf16)^T, 128x128 tile, BK=32
// EPI 0: store bf16. EPI 1: +bias, exact GELU, store bf16. EPI 2: +bias+resid, store f32.
// ---------------------------------------------------------------------------
template<int EPI>
__global__ __launch_bounds__(256) void gemm_bt(
    const ushort* __restrict__ A, const ushort* __restrict__ Bt,
    const float* __restrict__ bias, const float* __restrict__ resid,
    void* __restrict__ Cp, int Mrows, int Ncols, int K)
{
    __shared__ ushort As[128][40];   // +8 pad, rows stay 16B aligned (80 B stride)
    __shared__ ushort Bs[128][40];
    const int tid  = threadIdx.x;
    const int lane = tid & 63;
    const int w    = tid >> 6;
    const int wm   = (w >> 1) << 6;
    const int wn   = (w & 1) << 6;
    const int lr   = lane & 15;
    const int lq   = lane >> 4;
    const int m0   = blockIdx.y << 7;
    const int n0   = blockIdx.x << 7;
    const int srow = tid >> 2;
    const int sch  = (tid & 3) << 3;

    f32x4 acc[4][4];
    #pragma unroll
    for (int i = 0; i < 4; i++)
        #pragma unroll
        for (int j = 0; j < 4; j++)
            acc[i][j] = (f32x4){0.f, 0.f, 0.f, 0.f};

    for (int k0 = 0; k0 < K; k0 += 32) {
        *(uint4*)&As[srow][sch]      = *(const uint4*)&A[(size_t)(m0 + srow) * K + k0 + sch];
        *(uint4*)&As[srow + 64][sch] = *(const uint4*)&A[(size_t)(m0 + srow + 64) * K + k0 + sch];
        *(uint4*)&Bs[srow][sch]      = *(const uint4*)&Bt[(size_t)(n0 + srow) * K + k0 + sch];
        *(uint4*)&Bs[srow + 64][sch] = *(const uint4*)&Bt[(size_t)(n0 + srow + 64) * K + k0 + sch];
        __syncthreads();
        short8 af[4], bfr[4];
        #pragma unroll
        for (int i = 0; i < 4; i++) af[i]  = *(const short8*)&As[wm + i * 16 + lr][lq * 8];
        #pragma unroll
        for (int j = 0; j < 4; j++) bfr[j] = *(const short8*)&Bs[wn + j * 16 + lr][lq * 8];
        #pragma unroll
        for (int i = 0; i < 4; i++)
            #pragma unroll
            for (int j = 0; j < 4; j++)
                acc[i][j] = __builtin_amdgcn_mfma_f32_16x16x32_bf16(af[i], bfr[j], acc[i][j], 0, 0, 0);
        __syncthreads();
    }

    #pragma unroll
    for (int i = 0; i < 4; i++) {
        #pragma unroll
        for (int j = 0; j < 4; j++) {
            const int col = n0 + wn + j * 16 + lr;
            #pragma unroll
            for (int r = 0; r < 4; r++) {
                const int rw = m0 + wm + i * 16 + lq * 4 + r;   // C/D: col=lane&15, row=quad*4+reg
                float v = acc[i][j][r];
                if (EPI == 1) { v += bias[col]; v = 0.5f * v * (1.f + erff(v * 0.70710678118654752f)); }
                if (EPI == 2) {
                    v += bias[col] + resid[(size_t)rw * Ncols + col];
                    ((float*)Cp)[(size_t)rw * Ncols + col] = v;
                } else {
                    ((ushort*)Cp)[(size_t)rw * Ncols + col] = f2bf(v);
                }
            }
        }
    }
}

// ---------------------------------------------------------------------------
// K4: attention over 32 pooled tokens + residual + LayerNorm2 -> y (bf16)
// One thread per token; k/v for the batch staged in LDS.
// ---------------------------------------------------------------------------
__global__ __launch_bounds__(256) void attn_ln2_kernel(
    const ushort* __restrict__ q, const float* __restrict__ kbuf, const float* __restrict__ vbuf,
    const float* __restrict__ counts, const float* __restrict__ x,
    const float* __restrict__ g2, const float* __restrict__ b2,
    float* __restrict__ x2, ushort* __restrict__ ybf)
{
    __shared__ float kS[Hn * Mn * DHn];   // 32 KB
    __shared__ float vS[Hn * Mn * DHn];   // 32 KB
    __shared__ float mS[Mn];
    const int tid = threadIdx.x;
    const int b = blockIdx.x >> 5;
    const int n = ((blockIdx.x & 31) << 8) + tid;
    for (int i = tid; i < Hn * Mn * DHn; i += 256) {
        kS[i] = kbuf[(size_t)b * Hn * Mn * DHn + i];
        vS[i] = vbuf[(size_t)b * Hn * Mn * DHn + i];
    }
    if (tid < Mn) mS[tid] = counts[b * Mn + tid];
    __syncthreads();

    const size_t row = (size_t)b * Nn + n;
    float sum = 0.f, sum2 = 0.f;
    for (int h = 0; h < Hn; ++h) {
        float qh[32];
        const ushort* qp = q + row * Cn + h * DHn;
        #pragma unroll
        for (int i = 0; i < 4; ++i) {
            short8 qv = *(const short8*)(qp + i * 8);
            #pragma unroll
            for (int j = 0; j < 8; ++j) qh[i * 8 + j] = bf2f((ushort)qv[j]);
        }
        float p[32]; float mx = -FLT_MAX;
        #pragma unroll
        for (int m = 0; m < 32; ++m) {
            float sv;
            if (mS[m] >= 1.f) {
                sv = 0.f;
                const float* kp = &kS[(h * Mn + m) * DHn];
                #pragma unroll
                for (int dq = 0; dq < 8; ++dq) {
                    float4 k4 = *(const float4*)&kp[dq * 4];
                    sv += qh[dq*4+0]*k4.x + qh[dq*4+1]*k4.y + qh[dq*4+2]*k4.z + qh[dq*4+3]*k4.w;
                }
                sv *= 0.17677669529663687f;   // Dh^-0.5
            } else sv = -FLT_MAX;
            p[m] = sv; mx = fmaxf(mx, sv);
        }
        float den = 0.f;
        #pragma unroll
        for (int m = 0; m < 32; ++m) { float e = __expf(p[m] - mx); p[m] = e; den += e; }
        float inv = 1.f / den;
        float o[32];
        #pragma unroll
        for (int dd = 0; dd < 32; ++dd) o[dd] = 0.f;
        #pragma unroll
        for (int m = 0; m < 32; ++m) {
            float pm = p[m];
            const float* vp = &vS[(h * Mn + m) * DHn];
            #pragma unroll
            for (int dq = 0; dq < 8; ++dq) {
                float4 v4 = *(const float4*)&vp[dq * 4];
                o[dq*4+0] += pm*v4.x; o[dq*4+1] += pm*v4.y; o[dq*4+2] += pm*v4.z; o[dq*4+3] += pm*v4.w;
            }
        }
        #pragma unroll
        for (int dq = 0; dq < 8; ++dq) {
            float4 xv = *(const float4*)&x[row * Cn + h * DHn + dq * 4];
            float r0 = xv.x + o[dq*4+0]*inv;
            float r1 = xv.y + o[dq*4+1]*inv;
            float r2 = xv.z + o[dq*4+2]*inv;
            float r3 = xv.w + o[dq*4+3]*inv;
            *(float4*)&x2[row * Cn + h * DHn + dq * 4] = make_float4(r0, r1, r2, r3);
            sum  += r0 + r1 + r2 + r3;
            sum2 += r0*r0 + r1*r1 + r2*r2 + r3*r3;
        }
    }
    float mean = sum * (1.f / Cn);
    float var  = sum2 * (1.f / Cn) - mean * mean;
    float rr   = rsqrtf(var + 1e-5f);
    for (int i = 0; i < Cn / 4; ++i) {
        float4 xv = *(const float4*)&x2[row * Cn + i * 4];
        float4 gv = *(const float4*)&g2[i * 4];
        float4 bv = *(const float4*)&b2[i * 4];
        ushort4 ub;
        ub.x = f2bf((xv.x - mean) * rr * gv.x + bv.x);
        ub.y = f2bf((xv.y - mean) * rr * gv.y + bv.y);
        ub.z = f2bf((xv.z - mean) * rr * gv.z + bv.z);
        ub.w = f2bf((xv.w - mean) * rr * gv.w + bv.w);
        *(ushort4*)&ybf[row * Cn + i * 4] = ub;
    }
}

// ---------------------------------------------------------------------------
// Weight cast + transpose: W[R][Cc] f32 -> Wt[Cc][R] bf16
// ---------------------------------------------------------------------------
__global__ void wcast_kernel(const float* __restrict__ W, ushort* __restrict__ Wt, int R, int Cc)
{
    int idx = blockIdx.x * 256 + threadIdx.x;
    if (idx < R * Cc) {
        int r = idx / Cc, c = idx % Cc;
        Wt[(size_t)c * R + r] = f2bf(W[idx]);
    }
}

extern "C" void kernel_launch(void* const* d_in, const int* in_sizes, int n_in,
                              void* d_out, int out_size, void* d_ws, size_t ws_size,
                              hipStream_t stream)
{
    const float* x    = (const float*)d_in[0];
    const float* rot  = (const float*)d_in[1];
    const float* n1g  = (const float*)d_in[2];
    const float* n1b  = (const float*)d_in[3];
    const float* q_w  = (const float*)d_in[4];
    const float* kv_w = (const float*)d_in[5];
    const float* n2g  = (const float*)d_in[6];
    const float* n2b  = (const float*)d_in[7];
    const float* fc1w = (const float*)d_in[8];
    const float* fc1b = (const float*)d_in[9];
    const float* fc2w = (const float*)d_in[10];
    const float* fc2b = (const float*)d_in[11];

    char* ws = (char*)d_ws;
    // Workspace layout (~451 MB). h (268MB) aliases x_bf16+q_bf16 (dead by K5).
    const size_t XBF_OFF = 0;                  // 67108864  bf16 x_ [131072][256]
    const size_t QBF_OFF = 67108864ull;        // 67108864  bf16 q
    const size_t H_OFF   = 0;                  // 268435456 bf16 h [131072][1024] (aliases above)
    const size_t X2_OFF  = 268435456ull;       // 134217728 f32 x2
    const size_t Y_OFF   = 402653184ull;       // 67108864  bf16 y
    const size_t PL_OFF  = 469762048ull;       // 524288    f32 pooled [16][32][256]
    const size_t CT_OFF  = PL_OFF + 524288;    // 2048      f32 counts
    const size_t KB_OFF  = CT_OFF + 2048;      // 524288    f32 k [16][8][32][32]
    const size_t VB_OFF  = KB_OFF + 524288;    // 524288    f32 v
    const size_t QWT_OFF = VB_OFF + 524288;    // 131072    bf16 q_w^T
    const size_t F1T_OFF = QWT_OFF + 131072;   // 524288    bf16 fc1^T
    const size_t F2T_OFF = F1T_OFF + 524288;   // 524288    bf16 fc2^T

    ushort* xbf    = (ushort*)(ws + XBF_OFF);
    ushort* qbf    = (ushort*)(ws + QBF_OFF);
    ushort* hbf    = (ushort*)(ws + H_OFF);
    float*  x2     = (float*)(ws + X2_OFF);
    ushort* ybf    = (ushort*)(ws + Y_OFF);
    float*  pooled = (float*)(ws + PL_OFF);
    float*  counts = (float*)(ws + CT_OFF);
    float*  kbuf   = (float*)(ws + KB_OFF);
    float*  vbuf   = (float*)(ws + VB_OFF);
    ushort* qwT    = (ushort*)(ws + QWT_OFF);
    ushort* f1T    = (ushort*)(ws + F1T_OFF);
    ushort* f2T    = (ushort*)(ws + F2T_OFF);

    hipMemsetAsync(ws + PL_OFF, 0, 524288 + 2048, stream);
    wcast_kernel<<<dim3(256), 256, 0, stream>>>(q_w, qwT, 256, 256);
    wcast_kernel<<<dim3(1024), 256, 0, stream>>>(fc1w, f1T, 256, 1024);
    wcast_kernel<<<dim3(1024), 256, 0, stream>>>(fc2w, f2T, 1024, 256);

    ln1_pool_kernel<<<dim3(Bn * 64), 256, 0, stream>>>(x, rot, n1g, n1b, xbf, pooled, counts);
    kv_kernel<<<dim3(Bn * Mn), 256, 0, stream>>>(pooled, counts, kv_w, kbuf, vbuf);
    gemm_bt<0><<<dim3(2, 1024), 256, 0, stream>>>(xbf, qwT, nullptr, nullptr, qbf, Bn * Nn, Cn, Cn);
    attn_ln2_kernel<<<dim3(Bn * 32), 256, 0, stream>>>(qbf, kbuf, vbuf, counts, x, n2g, n2b, x2, ybf);
    gemm_bt<1><<<dim3(8, 1024), 256, 0, stream>>>(ybf, f1T, fc1b, nullptr, hbf, Bn * Nn, DFFn, Cn);
    gemm_bt<2><<<dim3(2, 1024), 256, 0, stream>>>(hbf, f2T, fc2b, x2, d_out, Bn * Nn, Cn, DFFn);
}

// Round 3
// 1094.137 us; speedup vs baseline: 1.5537x; 1.5062x over previous
//
#include <hip/hip_runtime.h>
#include <hip/hip_bf16.h>
#include <float.h>
#include <math.h>

#define Bn   16
#define Nn   8192
#define Cn   256
#define Hn   8
#define DHn  32
#define Mn   32      // N_HASHES * N_BUCKETS
#define DFFn 1024
#define TOK  64      // tokens per ln1 block

typedef __attribute__((ext_vector_type(8))) short short8;
typedef __attribute__((ext_vector_type(4))) float f32x4;

__device__ __forceinline__ float bf2f(ushort u) {
    union { unsigned int i; float f; } v; v.i = ((unsigned int)u) << 16; return v.f;
}
__device__ __forceinline__ ushort f2bf(float f) {
    union { float f; unsigned int i; } v; v.f = f;
    unsigned int r = (v.i + 0x7fffu + ((v.i >> 16) & 1u)) >> 16;
    return (ushort)r;
}

// ---------------------------------------------------------------------------
// K1: LN1 + LSH rotation/argmax + ATOMIC-FREE bucket pooling (scatter->gather)
// Block = 64 tokens of one batch, 4 waves (wave-per-token phase A).
// Phase A: LN -> xbf global + bf16 tile in LDS, rotation dots (reg weights,
//          compile-time indexed), argmax -> packed bucket ids in LDS.
// Phase B: gather — thread owns feature column, accumulates 32 buckets in
//          registers via compare-select-add; writes per-block partials.
// ---------------------------------------------------------------------------
__global__ __launch_bounds__(256, 4) void ln1_pool_kernel(
    const float* __restrict__ x, const float* __restrict__ rot,
    const float* __restrict__ g1, const float* __restrict__ b1,
    ushort* __restrict__ xbf, float* __restrict__ pool_part, float* __restrict__ cnt_part)
{
    __shared__ ushort xt[TOK][Cn];        // 32 KB bf16 x_hat tile
    __shared__ unsigned int idsS[TOK];    // packed 4x8bit bucket ids

    const int tid  = threadIdx.x;
    const int w    = tid >> 6, lane = tid & 63;
    const int o    = lane & 15;           // rotation output index (h*4+i)
    const int g    = lane >> 4;           // feature-chunk group
    const int fbase = g << 6;             // 64-feature chunk for dot

    // 64 rotation weights, COMPILE-TIME indexed everywhere -> true registers.
    float rwv[64];
    #pragma unroll
    for (int f = 0; f < 64; ++f) rwv[f] = rot[(fbase + f) * 16 + o];

    const int b  = blockIdx.x >> 7;           // 128 blocks per batch
    const int n0 = (blockIdx.x & 127) << 6;   // 64 tokens per block

    const float4 gv = *(const float4*)&g1[lane * 4];
    const float4 bv = *(const float4*)&b1[lane * 4];

    for (int it = 0; it < TOK / 4; ++it) {
        const int tloc = (it << 2) + w;
        const size_t roff = ((size_t)b * Nn + n0 + tloc) * Cn;
        float4 xv = *(const float4*)&x[roff + lane * 4];
        float s  = xv.x + xv.y + xv.z + xv.w;
        float s2 = xv.x * xv.x + xv.y * xv.y + xv.z * xv.z + xv.w * xv.w;
        #pragma unroll
        for (int msk = 1; msk < 64; msk <<= 1) { s += __shfl_xor(s, msk); s2 += __shfl_xor(s2, msk); }
        float mean = s * (1.f / Cn);
        float var  = s2 * (1.f / Cn) - mean * mean;
        float rr   = rsqrtf(var + 1e-5f);
        float xn[4];
        xn[0] = (xv.x - mean) * rr * gv.x + bv.x;
        xn[1] = (xv.y - mean) * rr * gv.y + bv.y;
        xn[2] = (xv.z - mean) * rr * gv.z + bv.z;
        xn[3] = (xv.w - mean) * rr * gv.w + bv.w;
        ushort4 ub; ub.x = f2bf(xn[0]); ub.y = f2bf(xn[1]); ub.z = f2bf(xn[2]); ub.w = f2bf(xn[3]);
        *(ushort4*)&xbf[roff + lane * 4] = ub;
        *(ushort4*)&xt[tloc][lane * 4] = ub;   // same-wave RAW below: in-order LDS

        // 16 rotation dots: lane computes output o over its 64-feature chunk,
        // reading the bf16 tile (4-way bank aliasing ~1.58x: acceptable).
        float d = 0.f;
        #pragma unroll
        for (int j = 0; j < 8; ++j) {
            short8 xs = *(const short8*)&xt[tloc][fbase + j * 8];
            #pragma unroll
            for (int u = 0; u < 8; ++u)
                d += bf2f((ushort)xs[u]) * rwv[j * 8 + u];
        }
        d += __shfl_xor(d, 16); d += __shfl_xor(d, 32);   // full 256-dot for output o

        float d0 = __shfl(d, (lane & 12));
        float d1 = __shfl(d, (lane & 12) | 1);
        float d2 = __shfl(d, (lane & 12) | 2);
        float d3 = __shfl(d, (lane & 12) | 3);
        int bk = 0; float bb = d0;
        if (d1  > bb) { bb = d1;  bk = 1; }
        if (d2  > bb) { bb = d2;  bk = 2; }
        if (d3  > bb) { bb = d3;  bk = 3; }
        if (-d0 > bb) { bb = -d0; bk = 4; }
        if (-d1 > bb) { bb = -d1; bk = 5; }
        if (-d2 > bb) { bb = -d2; bk = 6; }
        if (-d3 > bb) { bb = -d3; bk = 7; }
        const unsigned int bk0 = __shfl(bk, 0), bk1 = __shfl(bk, 4),
                           bk2 = __shfl(bk, 8), bk3 = __shfl(bk, 12);
        if (lane == 0)
            idsS[tloc] = bk0 | (bk1 << 8) | (bk2 << 16) | (bk3 << 24);
    }
    __syncthreads();

    // Phase B: gather. Thread owns feature column f=tid; 32 bucket accum regs.
    float pool[Mn];
    #pragma unroll
    for (int m = 0; m < Mn; ++m) pool[m] = 0.f;
    for (int t = 0; t < TOK; ++t) {
        const float xv = bf2f(xt[t][tid]);
        const unsigned int idw = idsS[t];
        #pragma unroll
        for (int h = 0; h < 4; ++h) {
            const unsigned int id = (idw >> (8 * h)) & 7u;
            #pragma unroll
            for (int mb = 0; mb < 8; ++mb)
                pool[h * 8 + mb] += (id == (unsigned int)mb) ? xv : 0.f;
        }
    }
    const size_t pbase = (size_t)blockIdx.x * (Mn * Cn);
    #pragma unroll
    for (int m = 0; m < Mn; ++m)
        pool_part[pbase + m * Cn + tid] = pool[m];

    // per-block bucket counts (threads 0..31)
    if (tid < Mn) {
        const int h = tid >> 3, mb = tid & 7;
        float c = 0.f;
        for (int t = 0; t < TOK; ++t)
            c += (((idsS[t] >> (8 * h)) & 255u) == (unsigned int)mb) ? 1.f : 0.f;
        cnt_part[blockIdx.x * Mn + tid] = c;
    }
}

// ---------------------------------------------------------------------------
// K2: reduce partials -> rp_x -> k,v  (fp32). One block per (b, m).
// Also writes final counts for the attention mask.
// ---------------------------------------------------------------------------
__global__ __launch_bounds__(256) void kv_kernel(
    const float* __restrict__ pool_part, const float* __restrict__ cnt_part,
    const float* __restrict__ kv_w, float* __restrict__ kbuf, float* __restrict__ vbuf,
    float* __restrict__ countsF)
{
    __shared__ float rp[Cn];
    const int tid = threadIdx.x;
    const int b = blockIdx.x >> 5;
    const int m = blockIdx.x & 31;

    float acc = 0.f, cnt = 0.f;
    for (int j = 0; j < 128; ++j) {
        const int blk = b * 128 + j;
        acc += pool_part[(size_t)blk * (Mn * Cn) + m * Cn + tid];
        cnt += cnt_part[blk * Mn + m];
    }
    rp[tid] = acc / (cnt + 1e-20f);
    if (tid == 0) countsF[b * Mn + m] = cnt;
    __syncthreads();

    float a0 = 0.f, a1 = 0.f;
    for (int f = 0; f < Cn; ++f) {
        float rv = rp[f];
        a0 += rv * kv_w[f * 512 + tid];
        a1 += rv * kv_w[f * 512 + 256 + tid];
    }
    const int h = tid >> 5, d = tid & 31;
    kbuf[(((size_t)b * Hn + h) * Mn + m) * DHn + d] = a0;
    vbuf[(((size_t)b * Hn + h) * Mn + m) * DHn + d] = a1;
}

// ---------------------------------------------------------------------------
// GEMM: C[M][N] = A[M][K](bf16) x Bt[N][K](bf16)^T, 128x128 tile, BK=32
// EPI 0: store bf16. EPI 1: +bias, exact GELU, store bf16. EPI 2: +bias+resid, store f32.
// ---------------------------------------------------------------------------
template<int EPI>
__global__ __launch_bounds__(256) void gemm_bt(
    const ushort* __restrict__ A, const ushort* __restrict__ Bt,
    const float* __restrict__ bias, const float* __restrict__ resid,
    void* __restrict__ Cp, int Mrows, int Ncols, int K)
{
    __shared__ ushort As[128][40];   // +8 pad, rows stay 16B aligned (80 B stride)
    __shared__ ushort Bs[128][40];
    const int tid  = threadIdx.x;
    const int lane = tid & 63;
    const int w    = tid >> 6;
    const int wm   = (w >> 1) << 6;
    const int wn   = (w & 1) << 6;
    const int lr   = lane & 15;
    const int lq   = lane >> 4;
    const int m0   = blockIdx.y << 7;
    const int n0   = blockIdx.x << 7;
    const int srow = tid >> 2;
    const int sch  = (tid & 3) << 3;

    f32x4 acc[4][4];
    #pragma unroll
    for (int i = 0; i < 4; i++)
        #pragma unroll
        for (int j = 0; j < 4; j++)
            acc[i][j] = (f32x4){0.f, 0.f, 0.f, 0.f};

    for (int k0 = 0; k0 < K; k0 += 32) {
        *(uint4*)&As[srow][sch]      = *(const uint4*)&A[(size_t)(m0 + srow) * K + k0 + sch];
        *(uint4*)&As[srow + 64][sch] = *(const uint4*)&A[(size_t)(m0 + srow + 64) * K + k0 + sch];
        *(uint4*)&Bs[srow][sch]      = *(const uint4*)&Bt[(size_t)(n0 + srow) * K + k0 + sch];
        *(uint4*)&Bs[srow + 64][sch] = *(const uint4*)&Bt[(size_t)(n0 + srow + 64) * K + k0 + sch];
        __syncthreads();
        short8 af[4], bfr[4];
        #pragma unroll
        for (int i = 0; i < 4; i++) af[i]  = *(const short8*)&As[wm + i * 16 + lr][lq * 8];
        #pragma unroll
        for (int j = 0; j < 4; j++) bfr[j] = *(const short8*)&Bs[wn + j * 16 + lr][lq * 8];
        #pragma unroll
        for (int i = 0; i < 4; i++)
            #pragma unroll
            for (int j = 0; j < 4; j++)
                acc[i][j] = __builtin_amdgcn_mfma_f32_16x16x32_bf16(af[i], bfr[j], acc[i][j], 0, 0, 0);
        __syncthreads();
    }

    #pragma unroll
    for (int i = 0; i < 4; i++) {
        #pragma unroll
        for (int j = 0; j < 4; j++) {
            const int col = n0 + wn + j * 16 + lr;
            #pragma unroll
            for (int r = 0; r < 4; r++) {
                const int rw = m0 + wm + i * 16 + lq * 4 + r;   // C/D: col=lane&15, row=quad*4+reg
                float v = acc[i][j][r];
                if (EPI == 1) { v += bias[col]; v = 0.5f * v * (1.f + erff(v * 0.70710678118654752f)); }
                if (EPI == 2) {
                    v += bias[col] + resid[(size_t)rw * Ncols + col];
                    ((float*)Cp)[(size_t)rw * Ncols + col] = v;
                } else {
                    ((ushort*)Cp)[(size_t)rw * Ncols + col] = f2bf(v);
                }
            }
        }
    }
}

// ---------------------------------------------------------------------------
// K4: attention over 32 pooled tokens + residual + LayerNorm2 -> y (bf16)
// One thread per token; k/v for the batch staged in LDS.
// ---------------------------------------------------------------------------
__global__ __launch_bounds__(256) void attn_ln2_kernel(
    const ushort* __restrict__ q, const float* __restrict__ kbuf, const float* __restrict__ vbuf,
    const float* __restrict__ counts, const float* __restrict__ x,
    const float* __restrict__ g2, const float* __restrict__ b2,
    float* __restrict__ x2, ushort* __restrict__ ybf)
{
    __shared__ float kS[Hn * Mn * DHn];   // 32 KB
    __shared__ float vS[Hn * Mn * DHn];   // 32 KB
    __shared__ float mS[Mn];
    const int tid = threadIdx.x;
    const int b = blockIdx.x >> 5;
    const int n = ((blockIdx.x & 31) << 8) + tid;
    for (int i = tid; i < Hn * Mn * DHn; i += 256) {
        kS[i] = kbuf[(size_t)b * Hn * Mn * DHn + i];
        vS[i] = vbuf[(size_t)b * Hn * Mn * DHn + i];
    }
    if (tid < Mn) mS[tid] = counts[b * Mn + tid];
    __syncthreads();

    const size_t row = (size_t)b * Nn + n;
    float sum = 0.f, sum2 = 0.f;
    for (int h = 0; h < Hn; ++h) {
        float qh[32];
        const ushort* qp = q + row * Cn + h * DHn;
        #pragma unroll
        for (int i = 0; i < 4; ++i) {
            short8 qv = *(const short8*)(qp + i * 8);
            #pragma unroll
            for (int j = 0; j < 8; ++j) qh[i * 8 + j] = bf2f((ushort)qv[j]);
        }
        float p[32]; float mx = -FLT_MAX;
        #pragma unroll
        for (int m = 0; m < 32; ++m) {
            float sv;
            if (mS[m] >= 1.f) {
                sv = 0.f;
                const float* kp = &kS[(h * Mn + m) * DHn];
                #pragma unroll
                for (int dq = 0; dq < 8; ++dq) {
                    float4 k4 = *(const float4*)&kp[dq * 4];
                    sv += qh[dq*4+0]*k4.x + qh[dq*4+1]*k4.y + qh[dq*4+2]*k4.z + qh[dq*4+3]*k4.w;
                }
                sv *= 0.17677669529663687f;   // Dh^-0.5
            } else sv = -FLT_MAX;
            p[m] = sv; mx = fmaxf(mx, sv);
        }
        float den = 0.f;
        #pragma unroll
        for (int m = 0; m < 32; ++m) { float e = __expf(p[m] - mx); p[m] = e; den += e; }
        float inv = 1.f / den;
        float o[32];
        #pragma unroll
        for (int dd = 0; dd < 32; ++dd) o[dd] = 0.f;
        #pragma unroll
        for (int m = 0; m < 32; ++m) {
            float pm = p[m];
            const float* vp = &vS[(h * Mn + m) * DHn];
            #pragma unroll
            for (int dq = 0; dq < 8; ++dq) {
                float4 v4 = *(const float4*)&vp[dq * 4];
                o[dq*4+0] += pm*v4.x; o[dq*4+1] += pm*v4.y; o[dq*4+2] += pm*v4.z; o[dq*4+3] += pm*v4.w;
            }
        }
        #pragma unroll
        for (int dq = 0; dq < 8; ++dq) {
            float4 xv = *(const float4*)&x[row * Cn + h * DHn + dq * 4];
            float r0 = xv.x + o[dq*4+0]*inv;
            float r1 = xv.y + o[dq*4+1]*inv;
            float r2 = xv.z + o[dq*4+2]*inv;
            float r3 = xv.w + o[dq*4+3]*inv;
            *(float4*)&x2[row * Cn + h * DHn + dq * 4] = make_float4(r0, r1, r2, r3);
            sum  += r0 + r1 + r2 + r3;
            sum2 += r0*r0 + r1*r1 + r2*r2 + r3*r3;
        }
    }
    float mean = sum * (1.f / Cn);
    float var  = sum2 * (1.f / Cn) - mean * mean;
    float rr   = rsqrtf(var + 1e-5f);
    for (int i = 0; i < Cn / 4; ++i) {
        float4 xv = *(const float4*)&x2[row * Cn + i * 4];
        float4 gv = *(const float4*)&g2[i * 4];
        float4 bv = *(const float4*)&b2[i * 4];
        ushort4 ub;
        ub.x = f2bf((xv.x - mean) * rr * gv.x + bv.x);
        ub.y = f2bf((xv.y - mean) * rr * gv.y + bv.y);
        ub.z = f2bf((xv.z - mean) * rr * gv.z + bv.z);
        ub.w = f2bf((xv.w - mean) * rr * gv.w + bv.w);
        *(ushort4*)&ybf[row * Cn + i * 4] = ub;
    }
}

// ---------------------------------------------------------------------------
// Weight cast + transpose: W[R][Cc] f32 -> Wt[Cc][R] bf16
// ---------------------------------------------------------------------------
__global__ void wcast_kernel(const float* __restrict__ W, ushort* __restrict__ Wt, int R, int Cc)
{
    int idx = blockIdx.x * 256 + threadIdx.x;
    if (idx < R * Cc) {
        int r = idx / Cc, c = idx % Cc;
        Wt[(size_t)c * R + r] = f2bf(W[idx]);
    }
}

extern "C" void kernel_launch(void* const* d_in, const int* in_sizes, int n_in,
                              void* d_out, int out_size, void* d_ws, size_t ws_size,
                              hipStream_t stream)
{
    const float* x    = (const float*)d_in[0];
    const float* rot  = (const float*)d_in[1];
    const float* n1g  = (const float*)d_in[2];
    const float* n1b  = (const float*)d_in[3];
    const float* q_w  = (const float*)d_in[4];
    const float* kv_w = (const float*)d_in[5];
    const float* n2g  = (const float*)d_in[6];
    const float* n2b  = (const float*)d_in[7];
    const float* fc1w = (const float*)d_in[8];
    const float* fc1b = (const float*)d_in[9];
    const float* fc2w = (const float*)d_in[10];
    const float* fc2b = (const float*)d_in[11];

    char* ws = (char*)d_ws;
    // Workspace layout. h (268MB) aliases xbf+qbf (dead by K5).
    // pool_part (67MB) aliases x2 region (dead before attn writes x2).
    const size_t XBF_OFF = 0;                  // 67108864  bf16 x_ [131072][256]
    const size_t QBF_OFF = 67108864ull;        // 67108864  bf16 q
    const size_t H_OFF   = 0;                  // 268435456 bf16 h (aliases above)
    const size_t X2_OFF  = 268435456ull;       // 134217728 f32 x2  (first 67MB: pool_part)
    const size_t PP_OFF  = X2_OFF;             // 67108864  f32 pool_part [2048][32][256]
    const size_t CP_OFF  = X2_OFF + 67108864;  // 262144    f32 cnt_part [2048][32]
    const size_t Y_OFF   = 402653184ull;       // 67108864  bf16 y
    const size_t CT_OFF  = 469762048ull;       // 2048      f32 countsF
    const size_t KB_OFF  = CT_OFF + 4096;      // 524288    f32 k [16][8][32][32]
    const size_t VB_OFF  = KB_OFF + 524288;    // 524288    f32 v
    const size_t QWT_OFF = VB_OFF + 524288;    // 131072    bf16 q_w^T
    const size_t F1T_OFF = QWT_OFF + 131072;   // 524288    bf16 fc1^T
    const size_t F2T_OFF = F1T_OFF + 524288;   // 524288    bf16 fc2^T

    ushort* xbf    = (ushort*)(ws + XBF_OFF);
    ushort* qbf    = (ushort*)(ws + QBF_OFF);
    ushort* hbf    = (ushort*)(ws + H_OFF);
    float*  x2     = (float*)(ws + X2_OFF);
    float*  ppart  = (float*)(ws + PP_OFF);
    float*  cpart  = (float*)(ws + CP_OFF);
    ushort* ybf    = (ushort*)(ws + Y_OFF);
    float*  countsF= (float*)(ws + CT_OFF);
    float*  kbuf   = (float*)(ws + KB_OFF);
    float*  vbuf   = (float*)(ws + VB_OFF);
    ushort* qwT    = (ushort*)(ws + QWT_OFF);
    ushort* f1T    = (ushort*)(ws + F1T_OFF);
    ushort* f2T    = (ushort*)(ws + F2T_OFF);

    wcast_kernel<<<dim3(256), 256, 0, stream>>>(q_w, qwT, 256, 256);
    wcast_kernel<<<dim3(1024), 256, 0, stream>>>(fc1w, f1T, 256, 1024);
    wcast_kernel<<<dim3(1024), 256, 0, stream>>>(fc2w, f2T, 1024, 256);

    ln1_pool_kernel<<<dim3(Bn * 128), 256, 0, stream>>>(x, rot, n1g, n1b, xbf, ppart, cpart);
    kv_kernel<<<dim3(Bn * Mn), 256, 0, stream>>>(ppart, cpart, kv_w, kbuf, vbuf, countsF);
    gemm_bt<0><<<dim3(2, 1024), 256, 0, stream>>>(xbf, qwT, nullptr, nullptr, qbf, Bn * Nn, Cn, Cn);
    attn_ln2_kernel<<<dim3(Bn * 32), 256, 0, stream>>>(qbf, kbuf, vbuf, countsF, x, n2g, n2b, x2, ybf);
    gemm_bt<1><<<dim3(8, 1024), 256, 0, stream>>>(ybf, f1T, fc1b, nullptr, hbf, Bn * Nn, DFFn, Cn);
    gemm_bt<2><<<dim3(2, 1024), 256, 0, stream>>>(hbf, f2T, fc2b, x2, d_out, Bn * Nn, Cn, DFFn);
}